// Round 8
// baseline (306.401 us; speedup 1.0000x reference)
//
#include <hip/hip_runtime.h>
#include <hip/hip_bf16.h>

// Effi_MVS: B=1, V=5, C=32, D=48, H=128, W=160, RATIO=8.
// Round 11: split k_warpvar's two jobs. The fused kernel spent ~54us of pure
// instruction issue (49% VALU of 111us) because the 864-FMA/voxel contraction
// + 448 weight loads ride on a latency-bound gather. R9 proved MFMA does the
// contraction but killed gather occupancy when fused. Split:
//   - k_warpvar_lite: gather+variance -> var HWC bf16 [DHW][32]
//     (lane-contiguous 64B stores; no weights, no contraction)
//   - k_contract: (27x32)x(32xDHW) GEMM via mfma_f32_16x16x32_bf16, LDS-free:
//     HWC makes each lane's dwordx4 read its exact A-fragment (layout
//     HW-verified in R9). HBM-floor kernel.
//   - k_upsample reverted to R6 8-out version (2-dx cost +13us, ledger).
//   - k_conv stays scalar (TLP > per-thread efficiency, 3x confirmed).

#define NV 5
#define NC 32
#define ND 48
#define NH 128
#define NW 160
#define HW (NH * NW)
#define DHW (ND * HW)

typedef __attribute__((ext_vector_type(2))) float f32x2;
typedef __attribute__((ext_vector_type(4))) float f32x4;
typedef __attribute__((ext_vector_type(2), aligned(4))) float f32x2u;
typedef __attribute__((ext_vector_type(8))) short short8;
typedef __attribute__((ext_vector_type(4))) unsigned int u32x4;

// ws layout (bytes)
#define OFF_M      0          // float M[4][12]
#define OFF_WFB    256        // bf16 wfB[2][64][8] = 2048
#define OFF_DEPTHF 4096       // float depthf[20480]
#define OFF_PRE    86016      // float pre[48*128*160] = 3,932,160
#define OFF_WV     4018176    // bf16 WV[27][DHW] = 53,084,160
#define OFF_VAR    57102336   // bf16 var[DHW][32] = 62,914,560
// total = 120,016,896 bytes

__device__ __forceinline__ uint32_t pack_bf16(float a, float b) {
  __hip_bfloat16 ba = __float2bfloat16(a), bb = __float2bfloat16(b);
  uint16_t ua, ub;
  __builtin_memcpy(&ua, &ba, 2);
  __builtin_memcpy(&ub, &bb, 2);
  return (uint32_t)ua | ((uint32_t)ub << 16);
}

// ---------------------------------------------------------------- K1: setup
__global__ void k_setup(const float* __restrict__ proj,
                        const float* __restrict__ wreg,
                        float* __restrict__ M,
                        unsigned short* __restrict__ wfB) {
  if (threadIdx.x != 0) return;
  double P[NV][2][4][4];
  for (int v = 0; v < NV; ++v)
    for (int m = 0; m < 2; ++m)
      for (int i = 0; i < 4; ++i)
        for (int j = 0; j < 4; ++j)
          P[v][m][i][j] = (double)proj[((v * 2 + m) * 4 + i) * 4 + j];
  double C[NV][4][4];
  for (int v = 0; v < NV; ++v) {
    for (int i = 0; i < 4; ++i)
      for (int j = 0; j < 4; ++j) C[v][i][j] = P[v][0][i][j];
    for (int i = 0; i < 3; ++i)
      for (int j = 0; j < 4; ++j) {
        double s = 0.0;
        for (int k = 0; k < 3; ++k) s += P[v][1][i][k] * P[v][0][k][j];
        C[v][i][j] = s;
      }
  }
  double a[4][8];
  for (int i = 0; i < 4; ++i)
    for (int j = 0; j < 4; ++j) { a[i][j] = C[0][i][j]; a[i][j + 4] = (i == j) ? 1.0 : 0.0; }
  for (int col = 0; col < 4; ++col) {
    int piv = col; double best = fabs(a[col][col]);
    for (int r = col + 1; r < 4; ++r) { double v = fabs(a[r][col]); if (v > best) { best = v; piv = r; } }
    if (piv != col)
      for (int j = 0; j < 8; ++j) { double t = a[col][j]; a[col][j] = a[piv][j]; a[piv][j] = t; }
    double pv = a[col][col];
    for (int j = 0; j < 8; ++j) a[col][j] /= pv;
    for (int r = 0; r < 4; ++r) if (r != col) {
      double f = a[r][col];
      for (int j = 0; j < 8; ++j) a[r][j] -= f * a[col][j];
    }
  }
  double inv[4][4];
  for (int i = 0; i < 4; ++i)
    for (int j = 0; j < 4; ++j) inv[i][j] = a[i][j + 4];
  for (int v = 1; v < NV; ++v) {
    float* m = M + (v - 1) * 12;
    for (int i = 0; i < 3; ++i) {
      double r[4] = {0, 0, 0, 0};
      for (int k = 0; k < 4; ++k) {
        double cv = C[v][i][k];
        for (int j = 0; j < 4; ++j) r[j] += cv * inv[k][j];
      }
      m[i * 3 + 0] = (float)r[0]; m[i * 3 + 1] = (float)r[1]; m[i * 3 + 2] = (float)r[2];
      m[9 + i] = (float)r[3];
    }
  }
  // B-fragment layout for mfma_f32_16x16x32_bf16 (HW-verified in R9):
  // lane l supplies col n = l&15 (tap), k = (l>>4)*8 + e
  for (int nt = 0; nt < 2; ++nt)
    for (int l = 0; l < 64; ++l)
      for (int e = 0; e < 8; ++e) {
        int tap = nt * 16 + (l & 15);
        int k = (l >> 4) * 8 + e;
        float val = (tap < 27) ? wreg[k * 27 + tap] : 0.f;
        __hip_bfloat16 b = __float2bfloat16(val);
        uint16_t u; __builtin_memcpy(&u, &b, 2);
        wfB[(nt * 64 + l) * 8 + e] = u;
      }
}

// --------------------------------------- K2a: warp + variance (gather only)
__global__ __launch_bounds__(256) void k_warpvar_lite(
    const float* __restrict__ feat,    // [5][32][128][160]
    const float* __restrict__ depthv,  // [48]
    const float* __restrict__ M,       // [4][12]
    unsigned short* __restrict__ varO) // [DHW][32] bf16 (HWC)
{
  int idx = blockIdx.x * 256 + threadIdx.x;   // [0, DHW)
  int x = idx % NW;
  int t1 = idx / NW;
  int y = t1 % NH;
  int d = t1 / NH;
  int pix = y * NW + x;
  float xf = (float)x, yf = (float)y;
  float df = depthv[d];

  int   off[4];
  float wA[4], wB[4];
  bool any4 = false;

#pragma unroll
  for (int v = 0; v < 4; ++v) {
    const float* m = M + v * 12;
    float rx = m[0] * xf + m[1] * yf + m[2];
    float ry = m[3] * xf + m[4] * yf + m[5];
    float rz = m[6] * xf + m[7] * yf + m[8];
    float px = rx * df + m[9];
    float py = ry * df + m[10];
    float pz = rz * df + m[11];
    float gx = px / pz;
    float gy = py / pz;
    float y0 = floorf(gy);
    float wy = gy - y0;
    bool two = (wy == 0.f) || (wy == 1.f);
    any4 = any4 || !two;
    float rowf = (wy == 0.f) ? y0 : (y0 + 1.f);  // single surviving y-row
    float x0 = floorf(gx);
    float wx = gx - x0;
    bool yok  = (rowf >= 0.f) && (rowf <= (float)(NH - 1));
    bool x0ok = (x0 >= 0.f) && (x0 <= (float)(NW - 1)) && yok;
    bool x1ok = (x0 >= -1.f) && (x0 <= (float)(NW - 2)) && yok;
    float rc = fminf(fmaxf(rowf, 0.f), (float)(NH - 1));
    float xc = fminf(fmaxf(x0, 0.f), (float)(NW - 1));
    int xi = (int)xc;
    int o = (int)rc * NW + xi;
    bool ddv = (o == HW - 1);          // absolute plane end: shift base by 1
    bool sv  = (x0 >= 0.f) && (xi <= NW - 2);  // e.y is a distinct valid tap1
    o -= ddv ? 1 : 0;
    float w0 = (1.f - wx) * (x0ok ? 1.f : 0.f);
    float w1 = wx * (x1ok ? 1.f : 0.f);
    float wsum = w0 + w1;
    wA[v] = ddv ? 0.f : (sv ? w0 : wsum);
    wB[v] = ddv ? wsum : (sv ? w1 : 0.f);
    off[v] = o;
  }

  uint32_t st[16];

  if (__builtin_expect(!any4, 1)) {
    // ---------- hot 2-tap path, 8-channel load batches
#pragma unroll
    for (int g = 0; g < NC; g += 8) {
      float f0[8];
      f32x2 e[8][4];
#pragma unroll
      for (int cc = 0; cc < 8; ++cc) {
        int c = g + cc;
        f0[cc] = feat[c * HW + pix];
#pragma unroll
        for (int v = 0; v < 4; ++v) {
          const float* fv = feat + ((v + 1) * NC + c) * HW;
          f32x2u t = *(const f32x2u*)(fv + off[v]);
          e[cc][v].x = t.x; e[cc][v].y = t.y;
        }
      }
      float vr[8];
#pragma unroll
      for (int cc = 0; cc < 8; ++cc) {
        float vs = f0[cc], vq = f0[cc] * f0[cc];
#pragma unroll
        for (int v = 0; v < 4; ++v) {
          float val = wA[v] * e[cc][v].x + wB[v] * e[cc][v].y;
          vs += val;
          vq += val * val;
        }
        vr[cc] = vq * 0.2f - (vs * 0.2f) * (vs * 0.2f);
      }
#pragma unroll
      for (int q = 0; q < 4; ++q)
        st[g / 2 + q] = pack_bf16(vr[2 * q], vr[2 * q + 1]);
    }
  } else {
    // ---------- general 4-tap fallback (cold)
    int cidx[16]; float cw[16];
#pragma unroll
    for (int v = 0; v < 4; ++v) {
      const float* m = M + v * 12;
      float rx = m[0] * xf + m[1] * yf + m[2];
      float ry = m[3] * xf + m[4] * yf + m[5];
      float rz = m[6] * xf + m[7] * yf + m[8];
      float px = rx * df + m[9];
      float py = ry * df + m[10];
      float pz = rz * df + m[11];
      float gx = px / pz;
      float gy = py / pz;
      float x0 = floorf(gx), y0 = floorf(gy);
      float wx = gx - x0, wy = gy - y0;
      float cxs[2] = {x0, x0 + 1.f}, cys[2] = {y0, y0 + 1.f};
      float wxs[2] = {1.f - wx, wx}, wys[2] = {1.f - wy, wy};
#pragma unroll
      for (int cy = 0; cy < 2; ++cy)
#pragma unroll
        for (int cx = 0; cx < 2; ++cx) {
          float fx = cxs[cx], fy = cys[cy];
          bool valid = (fx >= 0.f) && (fx <= (float)(NW - 1)) &&
                       (fy >= 0.f) && (fy <= (float)(NH - 1));
          float fxc = fminf(fmaxf(fx, 0.f), (float)(NW - 1));
          float fyc = fminf(fmaxf(fy, 0.f), (float)(NH - 1));
          int xi2 = (int)fxc, yi2 = (int)fyc;
          cidx[v * 4 + cy * 2 + cx] = yi2 * NW + xi2;
          cw[v * 4 + cy * 2 + cx] = wxs[cx] * wys[cy] * (valid ? 1.f : 0.f);
        }
    }
    for (int g = 0; g < NC; g += 2) {
      float vr[2];
#pragma unroll
      for (int cc = 0; cc < 2; ++cc) {
        int c = g + cc;
        float f0 = feat[c * HW + pix];
        float vs = f0, vq = f0 * f0;
#pragma unroll
        for (int v = 0; v < 4; ++v) {
          const float* fv = feat + ((v + 1) * NC + c) * HW;
          float val = cw[v * 4 + 0] * fv[cidx[v * 4 + 0]]
                    + cw[v * 4 + 1] * fv[cidx[v * 4 + 1]]
                    + cw[v * 4 + 2] * fv[cidx[v * 4 + 2]]
                    + cw[v * 4 + 3] * fv[cidx[v * 4 + 3]];
          vs += val;
          vq += val * val;
        }
        vr[cc] = vq * 0.2f - (vs * 0.2f) * (vs * 0.2f);
      }
      st[g / 2] = pack_bf16(vr[0], vr[1]);
    }
  }

  // 64 B contiguous per lane; wave covers a contiguous 16 KB block
  u32x4* dst = (u32x4*)((uint32_t*)varO + (size_t)idx * 16);
#pragma unroll
  for (int q = 0; q < 4; ++q) {
    u32x4 o4;
    o4.x = st[4 * q + 0]; o4.y = st[4 * q + 1];
    o4.z = st[4 * q + 2]; o4.w = st[4 * q + 3];
    dst[q] = o4;
  }
}

// --------------------------------- K2b: contraction GEMM (27x32)x(32xDHW)
__global__ __launch_bounds__(256) void k_contract(
    const unsigned short* __restrict__ varI,  // [DHW][32] bf16
    const unsigned short* __restrict__ wfB,   // [2][64][8] bf16 fragments
    unsigned short* __restrict__ WVu)         // [27][DHW] bf16
{
  int tid = threadIdx.x;
  int lane = tid & 63;
  int wavebase = blockIdx.x * 256 + (tid & ~63);   // wave's first voxel
  short8 bfr0 = *(const short8*)(wfB + (size_t)lane * 8);
  short8 bfr1 = *(const short8*)(wfB + (size_t)(64 + lane) * 8);
  int lr = lane & 15, lk = lane >> 4;
  uint32_t* W32 = (uint32_t*)WVu;

#pragma unroll
  for (int m = 0; m < 4; ++m) {
    // A-fragment: row = lane&15 (voxel), k = (lane>>4)*8.. — HWC direct load
    int voxA = wavebase + m * 16 + lr;
    short8 af = *(const short8*)(varI + (size_t)voxA * 32 + lk * 8);
    f32x4 z = {0.f, 0.f, 0.f, 0.f};
    f32x4 a0 = __builtin_amdgcn_mfma_f32_16x16x32_bf16(af, bfr0, z, 0, 0, 0);
    f32x4 a1 = __builtin_amdgcn_mfma_f32_16x16x32_bf16(af, bfr1, z, 0, 0, 0);
    // C layout: col = lane&15 (tap), row = (lane>>4)*4 + reg (voxel)
    int v4 = wavebase + m * 16 + lk * 4;
    size_t o0 = ((size_t)lr * DHW + v4) >> 1;
    W32[o0] = pack_bf16(a0[0], a0[1]);
    W32[o0 + 1] = pack_bf16(a0[2], a0[3]);
    int tap1 = 16 + lr;
    if (tap1 < 27) {
      size_t o1 = ((size_t)tap1 * DHW + v4) >> 1;
      W32[o1] = pack_bf16(a1[0], a1[1]);
      W32[o1 + 1] = pack_bf16(a1[2], a1[3]);
    }
  }
}

// ------------------------------------------------- K3a: 27-tap gather (conv)
__global__ __launch_bounds__(256) void k_conv(const __hip_bfloat16* __restrict__ WV,
                                              float* __restrict__ pre) {
  int idx = blockIdx.x * 256 + threadIdx.x;
  int x = idx % NW;
  int t1 = idx / NW;
  int y = t1 % NH;
  int d = t1 / NH;
  float acc = 0.f;
#pragma unroll
  for (int dd = 0; dd < 3; ++dd) {
    int dp = d + dd - 1;
    bool dok = (dp >= 0) && (dp < ND);
    int dpc = min(max(dp, 0), ND - 1);
#pragma unroll
    for (int i = 0; i < 3; ++i) {
      int yp = y + i - 1;
      bool yok = (yp >= 0) && (yp < NH);
      int ypc = min(max(yp, 0), NH - 1);
#pragma unroll
      for (int j = 0; j < 3; ++j) {
        int xp = x + j - 1;
        bool xok = (xp >= 0) && (xp < NW);
        int xpc = min(max(xp, 0), NW - 1);
        int t = dd * 9 + i * 3 + j;
        float v = __bfloat162float(WV[t * DHW + dpc * HW + ypc * NW + xpc]);
        acc += (dok && yok && xok) ? v : 0.f;
      }
    }
  }
  pre[idx] = acc;
}

// ---------------------------------------- K3b: softmax over D + depth + conf
__global__ __launch_bounds__(256) void k_softmax(const float* __restrict__ pre,
                                                 const float* __restrict__ depthv,
                                                 float* __restrict__ depthf,
                                                 float* __restrict__ out_depth,
                                                 float* __restrict__ out_conf) {
  int p = blockIdx.x * 256 + threadIdx.x;
  float pr[ND];
  float m = -1e30f;
#pragma unroll
  for (int d = 0; d < ND; ++d) { pr[d] = pre[d * HW + p]; m = fmaxf(m, pr[d]); }
  float s = 0.f;
#pragma unroll
  for (int d = 0; d < ND; ++d) { pr[d] = expf(pr[d] - m); s += pr[d]; }
  float inv = 1.f / s;
  float dep = 0.f, ti = 0.f;
#pragma unroll
  for (int d = 0; d < ND; ++d) {
    float prob = pr[d] * inv;
    pr[d] = prob;
    dep += prob * depthv[d];
    ti += prob * (float)d;
  }
  int di = (int)ti;
  di = di < 0 ? 0 : (di > ND - 1 ? ND - 1 : di);
  float conf = 0.f;
#pragma unroll
  for (int d = 0; d < ND; ++d)
    conf += (d >= di - 1 && d <= di + 2) ? pr[d] : 0.f;
  depthf[p] = dep;
  out_depth[p] = dep;
  out_conf[p] = conf;
}

// -------------------------------------------------- K4: convex upsample (x8)
// 8 outputs (dx 0..7) per thread — the R6 version (others-best config).
__global__ __launch_bounds__(256) void k_upsample(const float* __restrict__ mask,
                                                  const float* __restrict__ depthf,
                                                  float* __restrict__ out) {
  int idx = blockIdx.x * 256 + threadIdx.x;  // [0, HW*8)
  int x = idx % NW;
  int r = idx / NW;
  int y = r % NH;
  int dy = r / NH;                           // 0..7
  int pix = y * NW + x;

  float dv[9];
#pragma unroll
  for (int k = 0; k < 9; ++k) {
    int ky = y + k / 3 - 1;
    int kx = x + k % 3 - 1;
    bool ok = (ky >= 0) && (ky < NH) && (kx >= 0) && (kx < NW);
    int kyc = min(max(ky, 0), NH - 1);
    int kxc = min(max(kx, 0), NW - 1);
    float t = depthf[kyc * NW + kxc];
    dv[k] = ok ? t : 0.f;
  }

  float res[8];
#pragma unroll
  for (int dx = 0; dx < 8; ++dx) {
    float mv[9];
    float mmax = -1e30f;
#pragma unroll
    for (int k = 0; k < 9; ++k) {
      mv[k] = mask[(size_t)(k * 64 + dy * 8 + dx) * HW + pix];
      mmax = fmaxf(mmax, mv[k]);
    }
    float s = 0.f, acc = 0.f;
#pragma unroll
    for (int k = 0; k < 9; ++k) {
      float e = expf(mv[k] - mmax);
      s += e;
      acc += e * dv[k];
    }
    res[dx] = acc / s;
  }

  float* op = out + (size_t)(y * 8 + dy) * (NW * 8) + x * 8;
  f32x4 lo, hi;
  lo.x = res[0]; lo.y = res[1]; lo.z = res[2]; lo.w = res[3];
  hi.x = res[4]; hi.y = res[5]; hi.z = res[6]; hi.w = res[7];
  *(f32x4*)op = lo;
  *(f32x4*)(op + 4) = hi;
}

// ---------------------------------------------------------------- launcher
extern "C" void kernel_launch(void* const* d_in, const int* in_sizes, int n_in,
                              void* d_out, int out_size, void* d_ws, size_t ws_size,
                              hipStream_t stream) {
  const float* feat   = (const float*)d_in[0];
  const float* proj   = (const float*)d_in[1];
  const float* depthv = (const float*)d_in[2];
  const float* mask   = (const float*)d_in[3];
  const float* wreg   = (const float*)d_in[4];

  char* ws = (char*)d_ws;
  float* M       = (float*)(ws + OFF_M);
  unsigned short* wfB = (unsigned short*)(ws + OFF_WFB);
  float* depthf  = (float*)(ws + OFF_DEPTHF);
  float* pre     = (float*)(ws + OFF_PRE);
  unsigned short* WVu = (unsigned short*)(ws + OFF_WV);
  unsigned short* varB = (unsigned short*)(ws + OFF_VAR);
  const __hip_bfloat16* WV = (const __hip_bfloat16*)(ws + OFF_WV);

  float* out = (float*)d_out;
  float* out_depth = out + (NH * 8) * (NW * 8);
  float* out_conf  = out_depth + HW;

  k_setup<<<1, 64, 0, stream>>>(proj, wreg, M, wfB);
  k_warpvar_lite<<<DHW / 256, 256, 0, stream>>>(feat, depthv, M, varB);
  k_contract<<<DHW / 256, 256, 0, stream>>>(varB, wfB, WVu);
  k_conv<<<DHW / 256, 256, 0, stream>>>(WV, pre);
  k_softmax<<<HW / 256, 256, 0, stream>>>(pre, depthv, depthf, out_depth, out_conf);
  k_upsample<<<(NH * 8 * NW * 8 / 8) / 256, 256, 0, stream>>>(mask, depthf, out);
}